// Round 1
// baseline (6776.115 us; speedup 1.0000x reference)
//
#include <hip/hip_runtime.h>
#include <math.h>

#define Bn  8
#define Cn  64
#define Hn  192
#define Wn  256
#define HWc (Hn*Wn)
#define CHWc (Cn*HWc)
#define NCH 32
#define CWc 8

// cross-block sync state (re-zeroed every launch by zero_flags_k)
__device__ int   g_flags[Bn*NCH*Hn];          // [b][ch][row] : 1 = row done
__device__ float g_halo[Bn*NCH*2*2*Cn];       // [b][ch][side(0=L,1=R)][parity][ci]

__global__ void zero_flags_k() {
    int i = blockIdx.x * 256 + threadIdx.x;
    if (i < Bn*NCH*Hn) g_flags[i] = 0;
}

__global__ __launch_bounds__(256, 1) void seqconv_k(
    const float* __restrict__ X, const float* __restrict__ Wt,
    const float* __restrict__ Bias, float* __restrict__ Out)
{
    const int tid  = threadIdx.x;
    const int lane = tid & 63;     // = co for compute phase
    const int wave = tid >> 6;     // 0..3, ci group
    const int bid  = blockIdx.x;
    const int b    = bid & 7;      // batch  (bid%8 -> same XCD per batch)
    const int ch   = bid >> 3;     // width chunk 0..31
    const int w0   = ch * CWc;     // global w of local col 1
    const int ci0  = wave * 16;

    __shared__ __align__(16) float xin[3][12][68];  // [row slot][col 0..9][ci]
    __shared__ float red[4][8][72];                 // [wave][w][co]
    __shared__ float sbias[Cn];
    __shared__ __align__(16) float wstage[4608];

    const float* Xb = X  + (size_t)b * CHWc;
    float*       Ob = Out + (size_t)b * CHWc;

    if (tid < Cn) sbias[tid] = Bias[tid];

    // ---- load weights into registers: wreg[i][kh][kw] for ci = ci0+i, co = lane
    float wreg[144];
    for (int cc = 0; cc < 8; ++cc) {
        const float4* src = reinterpret_cast<const float4*>(Wt) + cc * 1152;
        for (int i = tid; i < 1152; i += 256)
            reinterpret_cast<float4*>(wstage)[i] = src[i];
        __syncthreads();
        if ((lane >> 3) == cc) {
            const int colo = lane & 7;
            #pragma unroll
            for (int i = 0; i < 16; ++i)
                #pragma unroll
                for (int k = 0; k < 9; ++k)
                    wreg[i*9 + k] = wstage[colo*576 + (ci0 + i)*9 + k];
        }
        __syncthreads();
    }

    // ---- per-thread staging tuples for one row (640 = 64ci x 10col)
    int  s_ci[3], s_col[3];
    bool s_act[3], s_ok[3];
    size_t s_off[3];
    #pragma unroll
    for (int k = 0; k < 3; ++k) {
        int idx = tid + 256*k;
        bool act = idx < 640;
        int ci  = act ? idx / 10 : 0;
        int col = act ? idx % 10 : 0;
        int gw  = w0 - 1 + col;
        bool ok = act && gw >= 0 && gw < Wn;
        s_ci[k] = ci; s_col[k] = col; s_act[k] = act; s_ok[k] = ok;
        s_off[k] = (size_t)ci * HWc + (ok ? gw : 0);
    }

    // ---- initial rows 0,1 into slots 0,1 (orig == updated), copy Out rows 0,1
    #pragma unroll
    for (int r = 0; r < 2; ++r) {
        #pragma unroll
        for (int k = 0; k < 3; ++k) if (s_act[k]) {
            float v = s_ok[k] ? Xb[s_off[k] + (size_t)r * Wn] : 0.f;
            xin[r][s_col[k]][s_ci[k]] = v;
        }
    }
    for (int idx = tid; idx < 2*Cn*CWc; idx += 256) {
        int r = idx >> 9, rem = idx & 511, ci = rem >> 3, wl = rem & 7;
        size_t o = (size_t)ci * HWc + (size_t)r * Wn + w0 + wl;
        Ob[o] = Xb[o];
    }

    const int rco = tid >> 3, rwl = tid & 7;  // reduce-phase mapping

    // prefetch original row 2
    float pf[3];
    #pragma unroll
    for (int k = 0; k < 3; ++k)
        pf[k] = s_ok[k] ? Xb[s_off[k] + (size_t)2 * Wn] : 0.f;

    __syncthreads();

    for (int pos = 2; pos < Hn; ++pos) {
        const int sA = (pos - 2) % 3, sB = (pos - 1) % 3, sC = pos % 3;

        // ---- wait for neighbors' row pos-1, pull updated halo columns
        if (pos >= 3) {
            if (tid == 0 && ch > 0) {
                while (__hip_atomic_load(&g_flags[(b*NCH + ch - 1)*Hn + pos - 1],
                        __ATOMIC_ACQUIRE, __HIP_MEMORY_SCOPE_AGENT) == 0) {}
            }
            if (tid == 1 && ch < NCH - 1) {
                while (__hip_atomic_load(&g_flags[(b*NCH + ch + 1)*Hn + pos - 1],
                        __ATOMIC_ACQUIRE, __HIP_MEMORY_SCOPE_AGENT) == 0) {}
            }
            __syncthreads();
            if (tid < Cn) {
                float v = 0.f;
                if (ch > 0)
                    v = __hip_atomic_load(&g_halo[(((b*NCH + ch - 1)*2 + 1)*2 + ((pos-1)&1))*Cn + tid],
                            __ATOMIC_ACQUIRE, __HIP_MEMORY_SCOPE_AGENT);
                xin[sB][0][tid] = v;
            } else if (tid < 2*Cn) {
                const int ci = tid - Cn;
                float v = 0.f;
                if (ch < NCH - 1)
                    v = __hip_atomic_load(&g_halo[(((b*NCH + ch + 1)*2 + 0)*2 + ((pos-1)&1))*Cn + ci],
                            __ATOMIC_ACQUIRE, __HIP_MEMORY_SCOPE_AGENT);
                xin[sB][9][ci] = v;
            }
        }

        // ---- commit prefetched original row pos into slot sC
        #pragma unroll
        for (int k = 0; k < 3; ++k)
            if (s_act[k]) xin[sC][s_col[k]][s_ci[k]] = pf[k];

        __syncthreads();

        // ---- issue prefetch of next original row (latency hides under compute)
        {
            const int nr = (pos + 1 < Hn) ? pos + 1 : pos;
            #pragma unroll
            for (int k = 0; k < 3; ++k)
                pf[k] = s_ok[k] ? Xb[s_off[k] + (size_t)nr * Wn] : 0.f;
        }

        // ---- compute partial y[co][w] over 16 ci (weights in registers)
        float acc[8] = {0.f,0.f,0.f,0.f,0.f,0.f,0.f,0.f};
        #pragma unroll
        for (int kh = 0; kh < 3; ++kh) {
            const float* xs = &xin[kh == 0 ? sA : (kh == 1 ? sB : sC)][0][0];
            #pragma unroll
            for (int col = 0; col < 10; ++col) {
                const float4 a0 = *reinterpret_cast<const float4*>(xs + col*68 + ci0);
                const float4 a1 = *reinterpret_cast<const float4*>(xs + col*68 + ci0 + 4);
                const float4 a2 = *reinterpret_cast<const float4*>(xs + col*68 + ci0 + 8);
                const float4 a3 = *reinterpret_cast<const float4*>(xs + col*68 + ci0 + 12);
                const float xv[16] = {a0.x,a0.y,a0.z,a0.w, a1.x,a1.y,a1.z,a1.w,
                                      a2.x,a2.y,a2.z,a2.w, a3.x,a3.y,a3.z,a3.w};
                #pragma unroll
                for (int i = 0; i < 16; ++i) {
                    #pragma unroll
                    for (int kw = 0; kw < 3; ++kw) {
                        const int w = col - kw;
                        if (w >= 0 && w < 8)
                            acc[w] = fmaf(wreg[i*9 + kh*3 + kw], xv[i], acc[w]);
                    }
                }
            }
        }

        // ---- cross-wave reduction, tanh, writes
        #pragma unroll
        for (int w = 0; w < 8; ++w) red[wave][w][lane] = acc[w];
        __syncthreads();

        #pragma unroll
        for (int h = 0; h < 2; ++h) {
            const int co = rco + 32*h;
            float y = red[0][rwl][co] + red[1][rwl][co] + red[2][rwl][co] + red[3][rwl][co]
                    + sbias[co];
            float t  = tanhf(y);
            float ov = xin[sC][rwl + 1][co];
            float nv = ov + t;
            Ob[(size_t)co * HWc + (size_t)pos * Wn + w0 + rwl] = nv;
            xin[sC][rwl + 1][co] = nv;
            if (rwl == 0)
                __hip_atomic_store(&g_halo[(((b*NCH + ch)*2 + 0)*2 + (pos&1))*Cn + co], nv,
                        __ATOMIC_RELAXED, __HIP_MEMORY_SCOPE_AGENT);
            if (rwl == 7)
                __hip_atomic_store(&g_halo[(((b*NCH + ch)*2 + 1)*2 + (pos&1))*Cn + co], nv,
                        __ATOMIC_RELAXED, __HIP_MEMORY_SCOPE_AGENT);
        }

        __threadfence();
        __syncthreads();
        if (tid == 0)
            __hip_atomic_store(&g_flags[(b*NCH + ch)*Hn + pos], 1,
                    __ATOMIC_RELEASE, __HIP_MEMORY_SCOPE_AGENT);
    }
}

extern "C" void kernel_launch(void* const* d_in, const int* in_sizes, int n_in,
                              void* d_out, int out_size, void* d_ws, size_t ws_size,
                              hipStream_t stream) {
    const float* X    = (const float*)d_in[0];
    const float* Wt   = (const float*)d_in[1];
    const float* Bias = (const float*)d_in[2];
    float*       Out  = (float*)d_out;

    hipLaunchKernelGGL(zero_flags_k, dim3(192), dim3(256), 0, stream);

    void* args[] = {(void*)&X, (void*)&Wt, (void*)&Bias, (void*)&Out};
    hipError_t e = hipLaunchCooperativeKernel((void*)seqconv_k, dim3(Bn*NCH), dim3(256),
                                              args, 0, stream);
    if (e != hipSuccess) {
        // fallback: 256 blocks <= 256 CUs are co-resident in practice
        hipLaunchKernelGGL(seqconv_k, dim3(Bn*NCH), dim3(256), 0, stream, X, Wt, Bias, Out);
    }
}

// Round 2
// 1043.210 us; speedup vs baseline: 6.4954x; 6.4954x over previous
//
#include <hip/hip_runtime.h>
#include <math.h>

#define Bn  8
#define Cn  64
#define Hn  192
#define Wn  256
#define HWc (Hn*Wn)
#define CHWc (Cn*HWc)
#define NCH 32
#define CWc 8

// cross-block sync state (re-zeroed every launch by zero_flags_k)
__device__ int   g_flags[Bn*NCH*Hn];          // [b][ch][row] : 1 = row done
__device__ float g_halo[Bn*NCH*2*2*Cn];       // [b][ch][side(0=L,1=R)][parity][ci]

__global__ void zero_flags_k() {
    int i = blockIdx.x * 256 + threadIdx.x;
    if (i < Bn*NCH*Hn) g_flags[i] = 0;
}

__global__ __launch_bounds__(256, 1) void seqconv_k(
    const float* __restrict__ X, const float* __restrict__ Wt,
    const float* __restrict__ Bias, float* __restrict__ Out)
{
    const int tid  = threadIdx.x;
    const int lane = tid & 63;     // = co for compute phase
    const int wave = tid >> 6;     // 0..3, ci group
    const int bid  = blockIdx.x;
    const int b    = bid & 7;      // batch  (bid%8 -> same XCD per batch)
    const int ch   = bid >> 3;     // width chunk 0..31
    const int w0   = ch * CWc;     // global w of local col 1
    const int ci0  = wave * 16;

    __shared__ __align__(16) float xin[3][12][68];  // [row slot][col 0..9][ci]
    __shared__ float red[4][8][72];                 // [wave][w][co]
    __shared__ float sbias[Cn];
    __shared__ __align__(16) float wstage[4608];

    const float* Xb = X  + (size_t)b * CHWc;
    float*       Ob = Out + (size_t)b * CHWc;

    if (tid < Cn) sbias[tid] = Bias[tid];

    // ---- load weights into registers: wreg[i][kh][kw] for ci = ci0+i, co = lane
    float wreg[144];
    for (int cc = 0; cc < 8; ++cc) {
        const float4* src = reinterpret_cast<const float4*>(Wt) + cc * 1152;
        for (int i = tid; i < 1152; i += 256)
            reinterpret_cast<float4*>(wstage)[i] = src[i];
        __syncthreads();
        if ((lane >> 3) == cc) {
            const int colo = lane & 7;
            #pragma unroll
            for (int i = 0; i < 16; ++i)
                #pragma unroll
                for (int k = 0; k < 9; ++k)
                    wreg[i*9 + k] = wstage[colo*576 + (ci0 + i)*9 + k];
        }
        __syncthreads();
    }

    // ---- per-thread staging tuples for one row (640 = 64ci x 10col)
    int  s_ci[3], s_col[3];
    bool s_act[3], s_ok[3];
    size_t s_off[3];
    #pragma unroll
    for (int k = 0; k < 3; ++k) {
        int idx = tid + 256*k;
        bool act = idx < 640;
        int ci  = act ? idx / 10 : 0;
        int col = act ? idx % 10 : 0;
        int gw  = w0 - 1 + col;
        bool ok = act && gw >= 0 && gw < Wn;
        s_ci[k] = ci; s_col[k] = col; s_act[k] = act; s_ok[k] = ok;
        s_off[k] = (size_t)ci * HWc + (ok ? gw : 0);
    }

    // ---- initial rows 0,1 into slots 0,1 (orig == updated), copy Out rows 0,1
    #pragma unroll
    for (int r = 0; r < 2; ++r) {
        #pragma unroll
        for (int k = 0; k < 3; ++k) if (s_act[k]) {
            float v = s_ok[k] ? Xb[s_off[k] + (size_t)r * Wn] : 0.f;
            xin[r][s_col[k]][s_ci[k]] = v;
        }
    }
    for (int idx = tid; idx < 2*Cn*CWc; idx += 256) {
        int r = idx >> 9, rem = idx & 511, ci = rem >> 3, wl = rem & 7;
        size_t o = (size_t)ci * HWc + (size_t)r * Wn + w0 + wl;
        Ob[o] = Xb[o];
    }

    const int rco = tid >> 3, rwl = tid & 7;  // reduce-phase mapping

    // prefetch original row 2
    float pf[3];
    #pragma unroll
    for (int k = 0; k < 3; ++k)
        pf[k] = s_ok[k] ? Xb[s_off[k] + (size_t)2 * Wn] : 0.f;

    __syncthreads();

    for (int pos = 2; pos < Hn; ++pos) {
        const int sA = (pos - 2) % 3, sB = (pos - 1) % 3, sC = pos % 3;

        // ---- wait for neighbors' row pos-1 (RELAXED poll — no L2 invalidates),
        //      then pull updated halo columns via coherent relaxed loads
        if (pos >= 3) {
            if (tid < 2) {
                const int nb = (tid == 0) ? ch - 1 : ch + 1;
                if (nb >= 0 && nb < NCH) {
                    const int* fp = &g_flags[(b*NCH + nb)*Hn + pos - 1];
                    while (__hip_atomic_load(fp, __ATOMIC_RELAXED,
                                             __HIP_MEMORY_SCOPE_AGENT) == 0) {}
                }
            }
            __syncthreads();
            if (tid < Cn) {
                float v = 0.f;
                if (ch > 0)
                    v = __hip_atomic_load(&g_halo[(((b*NCH + ch - 1)*2 + 1)*2 + ((pos-1)&1))*Cn + tid],
                            __ATOMIC_RELAXED, __HIP_MEMORY_SCOPE_AGENT);
                xin[sB][0][tid] = v;
            } else if (tid < 2*Cn) {
                const int ci = tid - Cn;
                float v = 0.f;
                if (ch < NCH - 1)
                    v = __hip_atomic_load(&g_halo[(((b*NCH + ch + 1)*2 + 0)*2 + ((pos-1)&1))*Cn + ci],
                            __ATOMIC_RELAXED, __HIP_MEMORY_SCOPE_AGENT);
                xin[sB][9][ci] = v;
            }
        }

        // ---- commit prefetched original row pos into slot sC
        #pragma unroll
        for (int k = 0; k < 3; ++k)
            if (s_act[k]) xin[sC][s_col[k]][s_ci[k]] = pf[k];

        __syncthreads();

        // ---- issue prefetch of next original row (latency hides under compute)
        {
            const int nr = (pos + 1 < Hn) ? pos + 1 : pos;
            #pragma unroll
            for (int k = 0; k < 3; ++k)
                pf[k] = s_ok[k] ? Xb[s_off[k] + (size_t)nr * Wn] : 0.f;
        }

        // ---- compute partial y[co][w] over 16 ci (weights in registers)
        float acc[8] = {0.f,0.f,0.f,0.f,0.f,0.f,0.f,0.f};
        #pragma unroll
        for (int kh = 0; kh < 3; ++kh) {
            const float* xs = &xin[kh == 0 ? sA : (kh == 1 ? sB : sC)][0][0];
            #pragma unroll
            for (int col = 0; col < 10; ++col) {
                const float4 a0 = *reinterpret_cast<const float4*>(xs + col*68 + ci0);
                const float4 a1 = *reinterpret_cast<const float4*>(xs + col*68 + ci0 + 4);
                const float4 a2 = *reinterpret_cast<const float4*>(xs + col*68 + ci0 + 8);
                const float4 a3 = *reinterpret_cast<const float4*>(xs + col*68 + ci0 + 12);
                const float xv[16] = {a0.x,a0.y,a0.z,a0.w, a1.x,a1.y,a1.z,a1.w,
                                      a2.x,a2.y,a2.z,a2.w, a3.x,a3.y,a3.z,a3.w};
                #pragma unroll
                for (int i = 0; i < 16; ++i) {
                    #pragma unroll
                    for (int kw = 0; kw < 3; ++kw) {
                        const int w = col - kw;
                        if (w >= 0 && w < 8)
                            acc[w] = fmaf(wreg[i*9 + kh*3 + kw], xv[i], acc[w]);
                    }
                }
            }
        }

        // ---- cross-wave reduction, tanh, writes
        #pragma unroll
        for (int w = 0; w < 8; ++w) red[wave][w][lane] = acc[w];
        __syncthreads();

        #pragma unroll
        for (int h = 0; h < 2; ++h) {
            const int co = rco + 32*h;
            float y = red[0][rwl][co] + red[1][rwl][co] + red[2][rwl][co] + red[3][rwl][co]
                    + sbias[co];
            float t  = tanhf(y);
            float ov = xin[sC][rwl + 1][co];
            float nv = ov + t;
            Ob[(size_t)co * HWc + (size_t)pos * Wn + w0 + rwl] = nv;
            xin[sC][rwl + 1][co] = nv;
            if (rwl == 0)
                __hip_atomic_store(&g_halo[(((b*NCH + ch)*2 + 0)*2 + (pos&1))*Cn + co], nv,
                        __ATOMIC_RELAXED, __HIP_MEMORY_SCOPE_AGENT);
            if (rwl == 7)
                __hip_atomic_store(&g_halo[(((b*NCH + ch)*2 + 1)*2 + (pos&1))*Cn + co], nv,
                        __ATOMIC_RELAXED, __HIP_MEMORY_SCOPE_AGENT);
        }

        // __syncthreads drains vmcnt(0) per-thread before s_barrier, so all
        // coherent halo stores are at the coherence point before the flag.
        __syncthreads();
        if (tid == 0)
            __hip_atomic_store(&g_flags[(b*NCH + ch)*Hn + pos], 1,
                    __ATOMIC_RELAXED, __HIP_MEMORY_SCOPE_AGENT);
    }
}

extern "C" void kernel_launch(void* const* d_in, const int* in_sizes, int n_in,
                              void* d_out, int out_size, void* d_ws, size_t ws_size,
                              hipStream_t stream) {
    const float* X    = (const float*)d_in[0];
    const float* Wt   = (const float*)d_in[1];
    const float* Bias = (const float*)d_in[2];
    float*       Out  = (float*)d_out;

    hipLaunchKernelGGL(zero_flags_k, dim3(192), dim3(256), 0, stream);

    void* args[] = {(void*)&X, (void*)&Wt, (void*)&Bias, (void*)&Out};
    hipError_t e = hipLaunchCooperativeKernel((void*)seqconv_k, dim3(Bn*NCH), dim3(256),
                                              args, 0, stream);
    if (e != hipSuccess) {
        // fallback: 256 blocks <= 256 CUs are co-resident in practice
        hipLaunchKernelGGL(seqconv_k, dim3(Bn*NCH), dim3(256), 0, stream, X, Wt, Bias, Out);
    }
}